// Round 1
// baseline (881.775 us; speedup 1.0000x reference)
//
#include <hip/hip_runtime.h>

// QuantMatMul: fake-quant(A) @ fake-quant(B), computed exactly via i8 MFMA.
// A: [4,4096,4096] fp32 -> folded to M=16384 rows. B: [4096,4096] fp32 (K x N).
// C = s_a*s_b * ( A'B' - zb*rowsumA[m] - za*colsumB[n] + K*za*zb ),  A',B' in i8.
//
// Round 3: 256x256 tile, 8 waves (2Mx4N), wave=128x64 (acc[4][2] of 32x32),
// true LDS double-buffer (2x64KiB), all prefetch global_load_lds issued at
// phase 1 of the tile (issue-to-drain = 3 MFMA phases >> HBM latency), 4
// phases/tile {ds_read -> s_barrier -> setprio(1) 8xMFMA setprio(0) ->
// s_barrier}, tile-end __syncthreads is the only vmcnt drain. XCD-bijective
// block swizzle. Quant layouts (XOR-swizzled 16B blocks in 128B spans) kept.

#define K_DIM 4096
#define N_COLS 4096
#define M_ROWS 16384

typedef __attribute__((ext_vector_type(4))) int int4v;
typedef __attribute__((ext_vector_type(16))) int int16v;

struct QParams { float sa, zpa, sb, zpb, sab, ra, rb; int za, zb; };

// ---- workspace layout (total ~80.1 MiB) ----
static const size_t OFF_AQ = 0;                                  // 64 MiB  i8 [16384][4096] (swizzled)
static const size_t OFF_BT = (size_t)64 << 20;                   // 16 MiB  i8 [4096][4096] (B^T, swizzled)
static const size_t OFF_RS = OFF_BT + ((size_t)16 << 20);        // 64 KiB  int rowsumA
static const size_t OFF_CS = OFF_RS + (size_t)M_ROWS * 4;        // 16 KiB  int colsumB
static const size_t OFF_MM = OFF_CS + (size_t)N_COLS * 4;        // 64 B    minmax enc
static const size_t OFF_PR = OFF_MM + 64;                        // params

// sortable encoding for float atomic min/max
__device__ __forceinline__ unsigned enc_f(float f) {
  unsigned u = __float_as_uint(f);
  return (u & 0x80000000u) ? ~u : (u | 0x80000000u);
}
__device__ __forceinline__ float dec_f(unsigned e) {
  unsigned u = (e & 0x80000000u) ? (e & 0x7fffffffu) : ~e;
  return __uint_as_float(u);
}

// reciprocal-multiply quantize: matches ref's clip(rint(x/s)+zp,0,255), -128 shift
__device__ __forceinline__ int quantize1(float x, float r, float zp) {
  return (int)(fminf(fmaxf(rintf(x * r) + zp, 0.0f), 255.0f)) - 128;
}

__device__ __forceinline__ void gload16(const void* g, void* l) {
  __builtin_amdgcn_global_load_lds(
      (const __attribute__((address_space(1))) unsigned int*)g,
      (__attribute__((address_space(3))) unsigned int*)l, 16, 0, 0);
}

__global__ void init_mm_k(unsigned* mm) {
  if (threadIdx.x == 0) {
    mm[0] = 0xFFFFFFFFu; mm[1] = 0u;   // A min/max (encoded)
    mm[2] = 0xFFFFFFFFu; mm[3] = 0u;   // B min/max
  }
}

// fused minmax over A (blocks 0..4095) and B (blocks 4096..5119)
__global__ __launch_bounds__(256) void minmax_k(const float4* __restrict__ A,
                                                const float4* __restrict__ B,
                                                unsigned* __restrict__ mm) {
  const bool isB = blockIdx.x >= 4096;
  const float4* __restrict__ x = isB ? B : A;
  const long n4 = isB ? (long)K_DIM * N_COLS / 4 : (long)M_ROWS * K_DIM / 4;
  const int nblk = isB ? 1024 : 4096;
  const int bid = isB ? (int)blockIdx.x - 4096 : (int)blockIdx.x;
  unsigned* m = mm + (isB ? 2 : 0);

  float lo = 3.402823466e38f, hi = -3.402823466e38f;
  long i = (long)bid * blockDim.x + threadIdx.x;
  const long stride = (long)nblk * blockDim.x;
  for (; i < n4; i += stride) {
    float4 v = x[i];
    lo = fminf(lo, fminf(fminf(v.x, v.y), fminf(v.z, v.w)));
    hi = fmaxf(hi, fmaxf(fmaxf(v.x, v.y), fmaxf(v.z, v.w)));
  }
  for (int off = 32; off; off >>= 1) {
    lo = fminf(lo, __shfl_down(lo, off));
    hi = fmaxf(hi, __shfl_down(hi, off));
  }
  __shared__ float slo[4], shi[4];
  const int t = threadIdx.x;
  if ((t & 63) == 0) { slo[t >> 6] = lo; shi[t >> 6] = hi; }
  __syncthreads();
  if (t == 0) {
    for (int w = 1; w < 4; w++) { lo = fminf(lo, slo[w]); hi = fmaxf(hi, shi[w]); }
    atomicMin(&m[0], enc_f(lo));
    atomicMax(&m[1], enc_f(hi));
  }
}

__global__ void params_k(const unsigned* __restrict__ mm, QParams* __restrict__ p) {
  if (threadIdx.x != 0) return;
  const float amin = dec_f(mm[0]), amax = dec_f(mm[1]);
  const float bmin = dec_f(mm[2]), bmax = dec_f(mm[3]);
  const float sa = fmaxf((amax - amin) / 255.0f, 1e-8f);
  const float sb = fmaxf((bmax - bmin) / 255.0f, 1e-8f);
  const float zpa = rintf(-amin / sa);
  const float zpb = rintf(-bmin / sb);
  p->sa = sa; p->zpa = zpa; p->sb = sb; p->zpb = zpb;
  p->sab = sa * sb;
  p->ra = 1.0f / sa;
  p->rb = 1.0f / sb;
  p->za = (int)zpa - 128;
  p->zb = (int)zpb - 128;
}

// one block per row: quantize + XOR-swizzle 16B blocks within 128B spans + rowsum
__global__ __launch_bounds__(256) void quantA_k(const float* __restrict__ A,
                                                signed char* __restrict__ Aq,
                                                int* __restrict__ rowsum,
                                                const QParams* __restrict__ p) {
  const float ra = p->ra, zpa = p->zpa;
  const int row = blockIdx.x, t = threadIdx.x;
  const float4* src = (const float4*)(A + (size_t)row * K_DIM);
  unsigned* dst = (unsigned*)(Aq + (size_t)row * K_DIM);
  int sum = 0;
#pragma unroll
  for (int j = 0; j < 4; j++) {
    const int d = j * 256 + t;           // logical dword index in row (0..1023)
    float4 v = src[d];
    int q0 = quantize1(v.x, ra, zpa);
    int q1 = quantize1(v.y, ra, zpa);
    int q2 = quantize1(v.z, ra, zpa);
    int q3 = quantize1(v.w, ra, zpa);
    sum += q0 + q1 + q2 + q3;
    // swizzle: 16B block bits (d>>2)&7 XOR (row&7)
    const int dsw = (d & ~0x1C) | ((((d >> 2) ^ row) & 7) << 2);
    dst[dsw] = ((unsigned)q0 & 255u) | (((unsigned)q1 & 255u) << 8) |
               (((unsigned)q2 & 255u) << 16) | (((unsigned)q3 & 255u) << 24);
  }
  for (int off = 32; off; off >>= 1) sum += __shfl_down(sum, off);
  __shared__ int sw[4];
  if ((t & 63) == 0) sw[t >> 6] = sum;
  __syncthreads();
  if (t == 0) rowsum[row] = sw[0] + sw[1] + sw[2] + sw[3];
}

// quantize B, transpose to Bt[N][K] via 64x64 LDS tile, XOR-swizzle 16B blocks
__global__ __launch_bounds__(256) void quantB_k(const float* __restrict__ B,
                                                signed char* __restrict__ Bt,
                                                const QParams* __restrict__ p) {
  const float rb = p->rb, zpb = p->zpb;
  __shared__ unsigned char s[64][72];
  const int n0 = blockIdx.x * 64, k0 = blockIdx.y * 64;
  const int t = threadIdx.x;
  const int kr = t >> 2, tl = t & 3;
  const float* rowp = B + (size_t)(k0 + kr) * N_COLS + n0;
#pragma unroll
  for (int j = 0; j < 4; j++) {
    const int fi = tl + j * 4;
    float4 v = *(const float4*)(rowp + fi * 4);
    int q0 = quantize1(v.x, rb, zpb);
    int q1 = quantize1(v.y, rb, zpb);
    int q2 = quantize1(v.z, rb, zpb);
    int q3 = quantize1(v.w, rb, zpb);
    *(unsigned*)&s[kr][fi * 4] = ((unsigned)q0 & 255u) | (((unsigned)q1 & 255u) << 8) |
                                 (((unsigned)q2 & 255u) << 16) | (((unsigned)q3 & 255u) << 24);
  }
  __syncthreads();
  const int nr = t >> 2;                 // output row within tile (n)
  const int kb = tl * 16;                // 16-byte K block within 64B chunk
  unsigned w[4];
#pragma unroll
  for (int jj = 0; jj < 4; jj++) {
    unsigned b0 = s[kb + jj * 4 + 0][nr];
    unsigned b1 = s[kb + jj * 4 + 1][nr];
    unsigned b2 = s[kb + jj * 4 + 2][nr];
    unsigned b3 = s[kb + jj * 4 + 3][nr];
    w[jj] = b0 | (b1 << 8) | (b2 << 16) | (b3 << 24);
  }
  int4v o = {(int)w[0], (int)w[1], (int)w[2], (int)w[3]};
  const int bo = k0 + kb;                // logical byte offset in row
  const int bsw = (bo & ~0x70) | ((((bo >> 4) ^ nr) & 7) << 4);  // swizzled
  *(int4v*)(Bt + (size_t)(n0 + nr) * K_DIM + bsw) = o;
}

// colsum of B' = rowsum of Bt (swizzle is within-row permutation -> sum invariant)
__global__ __launch_bounds__(256) void colsum_k(const signed char* __restrict__ Bt,
                                                int* __restrict__ colsum) {
  const int n = blockIdx.x, t = threadIdx.x;
  const int4v v = ((const int4v*)(Bt + (size_t)n * K_DIM))[t];
  int sum = 0;
#pragma unroll
  for (int c = 0; c < 4; c++) {
    unsigned w = (unsigned)v[c];
    sum += (int)(signed char)(w & 255u) + (int)(signed char)((w >> 8) & 255u) +
           (int)(signed char)((w >> 16) & 255u) + (int)(signed char)((w >> 24) & 255u);
  }
  for (int off = 32; off; off >>= 1) sum += __shfl_down(sum, off);
  __shared__ int sw[4];
  if ((t & 63) == 0) sw[t >> 6] = sum;
  __syncthreads();
  if (t == 0) colsum[n] = sw[0] + sw[1] + sw[2] + sw[3];
}

// ---- i8 GEMM: 256x256 tile, BK=128B, 8 waves (2Mx4N), wave = 128x64 ----
// One K-tile = 4 phases. Phase kk: 6 ds_read_b128 (4 A-frags + 2 B-frags),
// [phase 1 only: issue all 8 global_load_lds for tile kt+1 into other slot],
// s_barrier, setprio(1), 8 MFMA, setprio(0), s_barrier. Tile-end __syncthreads
// is the only vmcnt drain -- prefetch has ~3 MFMA phases of latency cover.
__device__ __forceinline__ void tile_phases(const signed char* __restrict__ gA,
                                            const signed char* __restrict__ gB,
                                            const signed char* cur, signed char* nxt,
                                            size_t kof_next, bool stage,
                                            int aoff, int boff, int off,
                                            int h, int swz, int16v (&acc)[4][2]) {
  const signed char* a_base = cur + aoff;
  const signed char* b_base = cur + 32768 + boff;
#pragma unroll
  for (int kk = 0; kk < 4; ++kk) {
    const int ca = ((2 * kk + h) ^ swz) << 4;   // swizzled 16B block within row
    int4v a0 = *(const int4v*)(a_base + ca);
    int4v a1 = *(const int4v*)(a_base + 32 * 128 + ca);
    int4v a2 = *(const int4v*)(a_base + 64 * 128 + ca);
    int4v a3 = *(const int4v*)(a_base + 96 * 128 + ca);
    int4v b0 = *(const int4v*)(b_base + ca);
    int4v b1 = *(const int4v*)(b_base + 32 * 128 + ca);
    if (kk == 0 && stage) {
#pragma unroll
      for (int r = 0; r < 4; ++r) {
        gload16(gA + (size_t)(64 * r) * K_DIM + kof_next, nxt + off + r * 8192);
        gload16(gB + (size_t)(64 * r) * K_DIM + kof_next, nxt + 32768 + off + r * 8192);
      }
    }
    __builtin_amdgcn_s_barrier();
    __builtin_amdgcn_s_setprio(1);
    acc[0][0] = __builtin_amdgcn_mfma_i32_32x32x32_i8(a0, b0, acc[0][0], 0, 0, 0);
    acc[0][1] = __builtin_amdgcn_mfma_i32_32x32x32_i8(a0, b1, acc[0][1], 0, 0, 0);
    acc[1][0] = __builtin_amdgcn_mfma_i32_32x32x32_i8(a1, b0, acc[1][0], 0, 0, 0);
    acc[1][1] = __builtin_amdgcn_mfma_i32_32x32x32_i8(a1, b1, acc[1][1], 0, 0, 0);
    acc[2][0] = __builtin_amdgcn_mfma_i32_32x32x32_i8(a2, b0, acc[2][0], 0, 0, 0);
    acc[2][1] = __builtin_amdgcn_mfma_i32_32x32x32_i8(a2, b1, acc[2][1], 0, 0, 0);
    acc[3][0] = __builtin_amdgcn_mfma_i32_32x32x32_i8(a3, b0, acc[3][0], 0, 0, 0);
    acc[3][1] = __builtin_amdgcn_mfma_i32_32x32x32_i8(a3, b1, acc[3][1], 0, 0, 0);
    __builtin_amdgcn_s_setprio(0);
    if (kk < 3) __builtin_amdgcn_s_barrier();
  }
  __syncthreads();   // drains vmcnt (tile kt+1 staged) + lgkm; slot handoff
}

__global__ __launch_bounds__(512, 2) void gemm_k(const signed char* __restrict__ Aq,
                                                 const signed char* __restrict__ Bt,
                                                 float* __restrict__ C,
                                                 const int* __restrict__ rowsum,
                                                 const int* __restrict__ colsum,
                                                 const QParams* __restrict__ p) {
  __shared__ signed char lds[131072];   // 2 slots x (A 32KB + B 32KB)
  const int t = threadIdx.x;

  // XCD-bijective swizzle: 1024 wgs, 8 XCDs, 128 wgs/XCD; n-fastest within XCD
  const int orig = blockIdx.x;
  const int wgid = (orig & 7) * 128 + (orig >> 3);
  const int m0 = (wgid >> 4) * 256;
  const int n0 = (wgid & 15) * 256;

  const int w = t >> 6, l = t & 63;
  const int wm = (w >> 2) * 128;        // 2 wave-rows of 128
  const int wn = (w & 3) * 64;          // 4 wave-cols of 64
  const int r32 = l & 31, h = l >> 5;
  const int swz = r32 & 7;
  const int aoff = (wm + r32) * 128;
  const int boff = (wn + r32) * 128;

  int16v acc[4][2] = {};

  // staging: thread t covers 16B at off; 4 rounds of 64 rows per matrix
  const int off = t * 16;
  const int srow = off >> 7, scol = off & 127;
  const signed char* gA = Aq + (size_t)(m0 + srow) * K_DIM + scol;
  const signed char* gB = Bt + (size_t)(n0 + srow) * K_DIM + scol;

  signed char* s0 = lds;
  signed char* s1 = lds + 65536;

  // prologue: stage tile 0 -> slot 0
#pragma unroll
  for (int r = 0; r < 4; ++r) {
    gload16(gA + (size_t)(64 * r) * K_DIM, s0 + off + r * 8192);
    gload16(gB + (size_t)(64 * r) * K_DIM, s0 + 32768 + off + r * 8192);
  }
  __syncthreads();

  for (int kth = 0; kth < 16; ++kth) {
    const int t1 = 2 * kth + 1;
    tile_phases(gA, gB, s0, s1, (size_t)(t1)*128, true, aoff, boff, off, h, swz, acc);
    tile_phases(gA, gB, s1, s0, (size_t)(t1 + 1) * 128, t1 + 1 < 32, aoff, boff, off, h, swz, acc);
  }

  // epilogue: integer zero-point corrections (exact), then scale.
  // C/D layout (32x32): col = lane&31, row = (reg&3) + 8*(reg>>2) + 4*(lane>>5)
  const float sab = p->sab;
  const int za = p->za, zb = p->zb;
  const int kzz = K_DIM * za * zb;
  const int col0 = n0 + wn + r32;
  const int cs0 = za * colsum[col0];
  const int cs1 = za * colsum[col0 + 32];
#pragma unroll
  for (int m = 0; m < 4; ++m) {
    const int rbase = m0 + wm + m * 32 + 4 * h;
#pragma unroll
    for (int r = 0; r < 16; ++r) {
      const int row = rbase + (r & 3) + 8 * (r >> 2);
      const int base = kzz - zb * rowsum[row];
      C[(size_t)row * N_COLS + col0] = sab * (float)(acc[m][0][r] + base - cs0);
      C[(size_t)row * N_COLS + col0 + 32] = sab * (float)(acc[m][1][r] + base - cs1);
    }
  }
}

extern "C" void kernel_launch(void* const* d_in, const int* in_sizes, int n_in,
                              void* d_out, int out_size, void* d_ws, size_t ws_size,
                              hipStream_t stream) {
  const float* A = (const float*)d_in[0];
  const float* B = (const float*)d_in[1];
  float* C = (float*)d_out;
  char* ws = (char*)d_ws;
  signed char* Aq = (signed char*)(ws + OFF_AQ);
  signed char* Bt = (signed char*)(ws + OFF_BT);
  int* rowsum = (int*)(ws + OFF_RS);
  int* colsum = (int*)(ws + OFF_CS);
  unsigned* mm = (unsigned*)(ws + OFF_MM);
  QParams* prm = (QParams*)(ws + OFF_PR);

  init_mm_k<<<1, 64, 0, stream>>>(mm);
  minmax_k<<<5120, 256, 0, stream>>>((const float4*)A, (const float4*)B, mm);
  params_k<<<1, 64, 0, stream>>>(mm, prm);
  quantA_k<<<M_ROWS, 256, 0, stream>>>(A, Aq, rowsum, prm);
  quantB_k<<<dim3(64, 64), 256, 0, stream>>>(B, Bt, prm);
  colsum_k<<<N_COLS, 256, 0, stream>>>(Bt, colsum);
  gemm_k<<<1024, 512, 0, stream>>>(Aq, Bt, C, rowsum, colsum, prm);
}